// Round 5
// baseline (157.422 us; speedup 1.0000x reference)
//
#include <hip/hip_runtime.h>

// UniformKernel: per-column (dim) moving average (K=10, replicate pad) over
// bins axis (n_bins=2048) + per-column normalization. x: (NB, DIM) f32.
//
// out(b,d) = window_sum(b,d) / (width * sum_i w[i]*x[i,d]),
// w[i] = # windows covering row i under edge clamping (K cancels).
//
// R5: cooperative path removed (R4: 630 us + not graph-capturable).
// Two-kernel scheme: k_colsum (weighted partials, edge-specialized pure-add
// interior loop) -> k_smooth2 (inline per-block scale reduction + register
// ring + nt stores). partial lives in d_ws (gated on ws_size, fallback =
// proven 3-kernel path). R4 counters proved x stays L3-resident across
// passes (FETCH 288 MB for both passes), so pass-2 reads are L3-served.

constexpr int NB   = 2048;
constexpr int DIM  = 32768;
constexpr int DIM4 = DIM / 4;
constexpr int CB   = DIM4 / 256;   // 32 column blocks
constexpr int RC   = 32;           // row chunks
constexpr int ROWS = NB / RC;      // 64 rows per chunk

typedef float v4f __attribute__((ext_vector_type(4)));

__device__ __forceinline__ int clampb(int j) { return min(max(j, 0), NB - 1); }

// # windows covering row i (interior=10; head 15,6,7,8,9; tail 9,8,7,21).
__device__ __forceinline__ float wrow(int i) {
    int a = min(i + 4, NB - 1) - max(i - 5, 0) + 1;
    if (i == 0)      a += 10;
    if (i == NB - 1) a += 15;
    return (float)a;
}

// Pass 1: weighted column partial sums. Interior chunks (30 of 32): pure
// vector add, one *10 at the end. Edge chunks: per-row weights.
__global__ __launch_bounds__(256) void k_colsum(const float* __restrict__ x,
                                                float* __restrict__ partial) {
    const int d4 = blockIdx.x * 256 + threadIdx.x;
    const int rc = blockIdx.y;
    const int r0 = rc * ROWS;
    const v4f* __restrict__ px = reinterpret_cast<const v4f*>(x) + d4;
    v4f acc = {0.f, 0.f, 0.f, 0.f};
    if (rc == 0 || rc == RC - 1) {
        #pragma unroll 8
        for (int i = r0; i < r0 + ROWS; ++i)
            acc += wrow(i) * px[(size_t)i * DIM4];
    } else {
        #pragma unroll 8
        for (int i = r0; i < r0 + ROWS; ++i)
            acc += px[(size_t)i * DIM4];
        acc *= 10.f;
    }
    reinterpret_cast<v4f*>(partial)[(size_t)rc * DIM4 + d4] = acc;
}

// Pass 2 (fused): reduce partials for this block's columns -> scale, then
// sliding window via 10-deep register ring, normalized nt stores.
__global__ __launch_bounds__(256, 4) void k_smooth2(const float* __restrict__ x,
                                                    const float* __restrict__ partial,
                                                    const float* __restrict__ bins,
                                                    float* __restrict__ out) {
    const int d4 = blockIdx.x * 256 + threadIdx.x;
    const int b0 = blockIdx.y * ROWS;
    const v4f* __restrict__ px = reinterpret_cast<const v4f*>(x) + d4;
    v4f* __restrict__ po = reinterpret_cast<v4f*>(out) + d4;

    // scale = 1/(width * wsum); partial is pre-weighted. 32 coalesced rows,
    // shared by the 32 blocks with equal blockIdx.x -> L2/L3-served.
    v4f s = {0.f, 0.f, 0.f, 0.f};
    {
        const v4f* __restrict__ pp = reinterpret_cast<const v4f*>(partial) + d4;
        #pragma unroll
        for (int k = 0; k < RC; ++k) s += pp[(size_t)k * DIM4];
    }
    const float width = bins[1] - bins[0];
    v4f sc;
    sc.x = 1.f / (width * s.x);
    sc.y = 1.f / (width * s.y);
    sc.z = 1.f / (width * s.z);
    sc.w = 1.f / (width * s.w);

    v4f prev[10], cur[10];
    #pragma unroll
    for (int m = 0; m < 10; ++m)
        prev[m] = px[(size_t)clampb(b0 - 4 + m) * DIM4];
    v4f S = prev[0];
    #pragma unroll
    for (int m = 1; m < 10; ++m) S += prev[m];

    constexpr int MAIN = ROWS - (ROWS % 10);  // 60
    for (int t0 = 0; t0 < MAIN; t0 += 10) {
        #pragma unroll
        for (int m = 0; m < 10; ++m)
            cur[m] = px[(size_t)min(b0 + t0 + m + 6, NB - 1) * DIM4];
        #pragma unroll
        for (int m = 0; m < 10; ++m) {
            v4f o = S * sc;
            __builtin_nontemporal_store(o, po + (size_t)(b0 + t0 + m) * DIM4);
            S += cur[m] - prev[m];
            prev[m] = cur[m];
        }
    }
    #pragma unroll
    for (int m = 0; m < ROWS % 10; ++m)
        cur[m] = px[(size_t)min(b0 + MAIN + m + 6, NB - 1) * DIM4];
    #pragma unroll
    for (int m = 0; m < ROWS % 10; ++m) {
        v4f o = S * sc;
        __builtin_nontemporal_store(o, po + (size_t)(b0 + MAIN + m) * DIM4);
        S += cur[m] - prev[m];
    }
}

// ---------------- fallback pieces (proven R2 path, 150 us) ----------------
__global__ __launch_bounds__(256) void k_scale(const float* __restrict__ partial,
                                               const float* __restrict__ bins,
                                               float* __restrict__ scale) {
    const int d4 = blockIdx.x * 256 + threadIdx.x;
    const v4f* __restrict__ pp = reinterpret_cast<const v4f*>(partial) + d4;
    v4f s = {0.f, 0.f, 0.f, 0.f};
    #pragma unroll
    for (int k = 0; k < RC; ++k) s += pp[(size_t)k * DIM4];
    const float width = bins[1] - bins[0];
    v4f r;
    r.x = 1.f / (width * s.x);
    r.y = 1.f / (width * s.y);
    r.z = 1.f / (width * s.z);
    r.w = 1.f / (width * s.w);
    reinterpret_cast<v4f*>(scale)[d4] = r;
}

__global__ __launch_bounds__(256) void k_smooth(const float* __restrict__ x,
                                                const float* __restrict__ scale,
                                                float* __restrict__ out) {
    const int d4 = blockIdx.x * 256 + threadIdx.x;
    const int b0 = blockIdx.y * ROWS;
    const v4f* __restrict__ px = reinterpret_cast<const v4f*>(x) + d4;
    v4f* __restrict__ po = reinterpret_cast<v4f*>(out) + d4;
    const v4f sc = reinterpret_cast<const v4f*>(scale)[d4];

    v4f prev[10], cur[10];
    #pragma unroll
    for (int m = 0; m < 10; ++m)
        prev[m] = px[(size_t)clampb(b0 - 4 + m) * DIM4];
    v4f S = prev[0];
    #pragma unroll
    for (int m = 1; m < 10; ++m) S += prev[m];

    constexpr int MAIN = ROWS - (ROWS % 10);
    for (int t0 = 0; t0 < MAIN; t0 += 10) {
        #pragma unroll
        for (int m = 0; m < 10; ++m)
            cur[m] = px[(size_t)min(b0 + t0 + m + 6, NB - 1) * DIM4];
        #pragma unroll
        for (int m = 0; m < 10; ++m) {
            v4f o = S * sc;
            __builtin_nontemporal_store(o, po + (size_t)(b0 + t0 + m) * DIM4);
            S += cur[m] - prev[m];
            prev[m] = cur[m];
        }
    }
    #pragma unroll
    for (int m = 0; m < ROWS % 10; ++m)
        cur[m] = px[(size_t)min(b0 + MAIN + m + 6, NB - 1) * DIM4];
    #pragma unroll
    for (int m = 0; m < ROWS % 10; ++m) {
        v4f o = S * sc;
        __builtin_nontemporal_store(o, po + (size_t)(b0 + MAIN + m) * DIM4);
        S += cur[m] - prev[m];
    }
}

extern "C" void kernel_launch(void* const* d_in, const int* in_sizes, int n_in,
                              void* d_out, int out_size, void* d_ws, size_t ws_size,
                              hipStream_t stream) {
    const float* x    = (const float*)d_in[0];   // densities (NB, DIM)
    const float* bins = (const float*)d_in[1];   // (NB,)
    float* out = (float*)d_out;

    const size_t partial_bytes = (size_t)RC * DIM * sizeof(float);  // 4 MB
    dim3 g(DIM4 / 256, RC);

    if (ws_size >= partial_bytes) {
        // 2-kernel path: partial in d_ws (fully written before read each call).
        float* partial = (float*)d_ws;
        k_colsum<<<g, 256, 0, stream>>>(x, partial);
        k_smooth2<<<g, 256, 0, stream>>>(x, partial, bins, out);
    } else {
        // Fallback (proven): partial in out head, scale (128 KB) in d_ws.
        float* partial = out;
        float* scale   = (float*)d_ws;
        k_colsum<<<g, 256, 0, stream>>>(x, partial);
        k_scale<<<DIM4 / 256, 256, 0, stream>>>(partial, bins, scale);
        k_smooth<<<g, 256, 0, stream>>>(x, scale, out);
    }
}

// Round 6
// 130.215 us; speedup vs baseline: 1.2089x; 1.2089x over previous
//
#include <hip/hip_runtime.h>

// UniformKernel: per-column (dim) moving average (K=10, replicate pad) over
// bins axis (n_bins=2048) + per-column normalization. x: (NB, DIM) f32.
//
// out(b,d) = window_sum(b,d) / (width * sum_i w[i]*x[i,d]),
// w[i] = # windows covering row i under edge clamping (K cancels).
//
// R6: SINGLE-KERNEL design. The normalizer is a per-column reduction, so a
// block that owns a column stripe for ALL rows needs only __syncthreads:
//   phase A: weighted column sums (block-local, LDS tree reduce)
//   phase B: ring-window pass + normalized nt stores (proven R2 loop)
// No grid sync, no scratch buffers, no inter-kernel drains. Blocks skew ->
// chip-level read/write overlap. Steady state (R4 evidence): x is
// L3-resident across graph replays; HBM traffic ~= the 266 MB of nt writes.

constexpr int NB   = 2048;
constexpr int DIM  = 32768;
constexpr int DIM4 = DIM / 4;

constexpr int W4     = 16;            // float4 columns per block (64 floats)
constexpr int NBLK   = DIM4 / W4;     // 512 blocks = 2 per CU
constexpr int NTHR   = 512;           // 16 col-lanes x 32 row-groups
constexpr int RG     = NTHR / W4;     // 32 row-groups
constexpr int ROWS   = NB / RG;       // 64 rows per thread

typedef float v4f __attribute__((ext_vector_type(4)));

__device__ __forceinline__ int clampb(int j) { return min(max(j, 0), NB - 1); }

// # windows covering row i (interior=10; head 15,6,7,8,9; tail 9,8,7,21).
__device__ __forceinline__ float wrow(int i) {
    int a = min(i + 4, NB - 1) - max(i - 5, 0) + 1;
    if (i == 0)      a += 10;
    if (i == NB - 1) a += 15;
    return (float)a;
}

__global__ __launch_bounds__(NTHR, 4) void k_onepass(const float* __restrict__ x,
                                                     const float* __restrict__ bins,
                                                     float* __restrict__ out) {
    const int t  = threadIdx.x;
    const int c  = t & (W4 - 1);          // float4-column within stripe
    const int rg = t >> 4;                // row group (0..31)
    const int d4 = blockIdx.x * W4 + c;   // global float4 column
    const int b0 = rg * ROWS;             // first row of this thread
    const v4f* __restrict__ px = reinterpret_cast<const v4f*>(x) + d4;

    __shared__ v4f sums[RG][W4];          // 8 KB

    // ---- phase A: weighted partial column sums over this thread's rows.
    {
        v4f acc = {0.f, 0.f, 0.f, 0.f};
        if (rg == 0 || rg == RG - 1) {
            #pragma unroll 8
            for (int i = b0; i < b0 + ROWS; ++i)
                acc += wrow(i) * px[(size_t)i * DIM4];
        } else {
            #pragma unroll 8
            for (int i = b0; i < b0 + ROWS; ++i)
                acc += px[(size_t)i * DIM4];
            acc *= 10.f;
        }
        sums[rg][c] = acc;
    }
    __syncthreads();

    // ---- LDS tree reduce over row groups (fixed order -> deterministic).
    #pragma unroll
    for (int s = RG / 2; s > 0; s >>= 1) {
        if (rg < s) sums[rg][c] += sums[rg + s][c];
        __syncthreads();
    }

    const float width = bins[1] - bins[0];
    const v4f wsum = sums[0][c];
    v4f sc;
    sc.x = 1.f / (width * wsum.x);
    sc.y = 1.f / (width * wsum.y);
    sc.z = 1.f / (width * wsum.z);
    sc.w = 1.f / (width * wsum.w);

    // ---- phase B: sliding window via 10-deep register ring (proven loop),
    // reads L2/L3-warm (phase A just streamed the stripe), nt stores.
    v4f* __restrict__ po = reinterpret_cast<v4f*>(out) + d4;

    v4f prev[10], cur[10];
    #pragma unroll
    for (int m = 0; m < 10; ++m)
        prev[m] = px[(size_t)clampb(b0 - 4 + m) * DIM4];
    v4f S = prev[0];
    #pragma unroll
    for (int m = 1; m < 10; ++m) S += prev[m];

    constexpr int MAIN = ROWS - (ROWS % 10);  // 60
    for (int t0 = 0; t0 < MAIN; t0 += 10) {
        #pragma unroll
        for (int m = 0; m < 10; ++m)
            cur[m] = px[(size_t)min(b0 + t0 + m + 6, NB - 1) * DIM4];
        #pragma unroll
        for (int m = 0; m < 10; ++m) {
            v4f o = S * sc;
            __builtin_nontemporal_store(o, po + (size_t)(b0 + t0 + m) * DIM4);
            S += cur[m] - prev[m];
            prev[m] = cur[m];
        }
    }
    #pragma unroll
    for (int m = 0; m < ROWS % 10; ++m)
        cur[m] = px[(size_t)min(b0 + MAIN + m + 6, NB - 1) * DIM4];
    #pragma unroll
    for (int m = 0; m < ROWS % 10; ++m) {
        v4f o = S * sc;
        __builtin_nontemporal_store(o, po + (size_t)(b0 + MAIN + m) * DIM4);
        S += cur[m] - prev[m];
    }
}

extern "C" void kernel_launch(void* const* d_in, const int* in_sizes, int n_in,
                              void* d_out, int out_size, void* d_ws, size_t ws_size,
                              hipStream_t stream) {
    const float* x    = (const float*)d_in[0];   // densities (NB, DIM)
    const float* bins = (const float*)d_in[1];   // (NB,)
    float* out = (float*)d_out;
    k_onepass<<<dim3(NBLK), dim3(NTHR), 0, stream>>>(x, bins, out);
}